// Round 19
// baseline (190.200 us; speedup 1.0000x reference)
//
#include <hip/hip_runtime.h>
#include <hip/hip_bf16.h>
#include <math.h>

typedef unsigned short u16;
typedef unsigned int   u32;
typedef unsigned long long u64;
typedef __attribute__((ext_vector_type(8))) short short8;   // 8 bf16 (4 VGPR)
typedef __attribute__((ext_vector_type(4))) float f32x4;

// ---------------- problem constants ----------------
#define NHEADS 16
#define HD     32
#define WA     49
#define NROLL  132
#define NKV    181     // WA + NROLL
#define NKVT   192     // 12 tiles of 16
#define CDIM   512
#define QKVLD  1536
#define NPIX   25088   // 8*56*56
#define NWIN   512
// LDS pitches (bf16 elems)
#define VP  200       // Vt pitch
#define PSP 68        // Ps pitch (64 cols = one group + 4 pad)
#define LOG2E 1.4426950408889634f

__device__ __forceinline__ u16 f32_to_bf16(float f) {
    union { float f; u32 u; } x; x.f = f;
    u32 r = x.u + 0x7FFFu + ((x.u >> 16) & 1u);   // RNE
    return (u16)(r >> 16);
}
__device__ __forceinline__ u16 cvt_bf16_hw(float f) {
    __hip_bfloat16 h = __float2bfloat16(f);       // RNE
    return *reinterpret_cast<u16*>(&h);
}

// ---------------- fused fp32 -> bf16 conversion (3 buffers, 1 launch) ----------------
__global__ __launch_bounds__(256) void cvt3_bf16(
    const float* __restrict__ in0, u16* __restrict__ out0, int n0,
    const float* __restrict__ in1, u16* __restrict__ out1, int n1,
    const float* __restrict__ in2, u16* __restrict__ out2, int n2)
{
    int i = (blockIdx.x * 256 + threadIdx.x) * 4;
    const float* in; u16* out;
    if (i < n0)            { in = in0; out = out0; }
    else if (i < n0 + n1)  { in = in1; out = out1; i -= n0; }
    else if (i < n0 + n1 + n2) { in = in2; out = out2; i -= n0 + n1; }
    else return;
    float4 v = *(const float4*)(in + i);
    *(ushort4*)(out + i) = make_ushort4(f32_to_bf16(v.x), f32_to_bf16(v.y),
                                        f32_to_bf16(v.z), f32_to_bf16(v.w));
}

// ---------------- bias table, swapped-QK^T C-fragment order, pre-scaled by log2e ----------------
// bt[head][qt(4)][n(12)][lane(64)][r(4)]:
//   qi = qt*16 + (lane&15) ; kv = n*16 + (lane>>4)*4 + r.  Mask baked (-1e30*log2e).
__global__ __launch_bounds__(256) void build_bias(
    const float* __restrict__ rpbt,   // (169,16)
    const float* __restrict__ rpbn,   // (16,49,132)
    float* __restrict__ bt)
{
    const int idx  = blockIdx.x * 256 + threadIdx.x;
    const int h    = idx / 12288;            // 4*12*64*4
    const int rem  = idx % 12288;
    const int qt   = rem / 3072;             // 12*64*4
    const int rem2 = rem % 3072;
    const int n    = rem2 / 256;             // 64*4
    const int rem3 = rem2 % 256;
    const int lane = rem3 / 4;
    const int r    = rem3 % 4;
    const int qi = qt * 16 + (lane & 15);
    const int kv = n * 16 + (lane >> 4) * 4 + r;
    float v = -1e30f;
    if (qi < WA && kv < NKV) {
        if (kv < WA) {
            const int r1 = qi / 7, c1 = qi % 7, r2 = kv / 7, c2 = kv % 7;
            v = rpbt[((r1 - r2 + 6) * 13 + (c1 - c2 + 6)) * NHEADS + h];
        } else {
            v = rpbn[(h * WA + qi) * NROLL + (kv - WA)];
        }
    }
    bt[idx] = v * LOG2E;                     // fold log2e: attn uses exp2 directly
}

// ---------------- bf16 MFMA GEMM: C = A @ W^T + bias, BK=64 ----------------
// 1D grid with XCD-chunked swizzle (gridDim.x divisible by 8).
// __launch_bounds__(256,4): cap VGPR at 128 so 4 blocks/CU at 32KB LDS (r18: -21us).
template<bool STORE_BF16>
__global__ __launch_bounds__(256, 4) void gemm_mfma(
    const u16* __restrict__ A, const u16* __restrict__ W,
    const float* __restrict__ bias, void* __restrict__ Cv,
    int M, int N, int K)
{
    __shared__ __align__(16) u16 As[128 * 64];   // 16 KB
    __shared__ __align__(16) u16 Bs[128 * 64];   // 16 KB
    const int tid = threadIdx.x;
    const int lane = tid & 63, wv = tid >> 6;
    const int bid = blockIdx.x;
    const int nid = (bid & 7) * (gridDim.x >> 3) + (bid >> 3);
    const int nbx = N >> 7;
    const int m0 = (nid / nbx) * 128, n0 = (nid % nbx) * 128;
    const int wr = (wv >> 1) * 64, wc = (wv & 1) * 64;
    const int lr = lane & 15;
    const int lk = (lane >> 4) * 8;
    const int srow = lane >> 3;          // 0..7 within 8-row block
    const int scol = (lane & 7) * 8;     // 0..56 elems

    f32x4 acc[4][4] = {};

    for (int k0 = 0; k0 < K; k0 += 64) {
        __syncthreads();
        #pragma unroll
        for (int blk = 0; blk < 4; ++blk) {
            const int r = wv * 32 + blk * 8;     // 8 rows per instr (64 lanes x 16B = 1KB)
            __builtin_amdgcn_global_load_lds(
                (const __attribute__((address_space(1))) void*)
                    (A + (size_t)(m0 + r + srow) * K + k0 + scol),
                (__attribute__((address_space(3))) void*)(As + r * 64), 16, 0, 0);
            __builtin_amdgcn_global_load_lds(
                (const __attribute__((address_space(1))) void*)
                    (W + (size_t)(n0 + r + srow) * K + k0 + scol),
                (__attribute__((address_space(3))) void*)(Bs + r * 64), 16, 0, 0);
        }
        __syncthreads();
        #pragma unroll
        for (int kk = 0; kk < 2; ++kk) {
            short8 af[4], bf[4];
            #pragma unroll
            for (int mi = 0; mi < 4; ++mi)
                af[mi] = *(const short8*)(As + (wr + mi * 16 + lr) * 64 + kk * 32 + lk);
            #pragma unroll
            for (int ni = 0; ni < 4; ++ni)
                bf[ni] = *(const short8*)(Bs + (wc + ni * 16 + lr) * 64 + kk * 32 + lk);
            #pragma unroll
            for (int mi = 0; mi < 4; ++mi)
                #pragma unroll
                for (int ni = 0; ni < 4; ++ni)
                    acc[mi][ni] = __builtin_amdgcn_mfma_f32_16x16x32_bf16(af[mi], bf[ni], acc[mi][ni], 0, 0, 0);
        }
    }

    const int hi = lane >> 4;
    if (STORE_BF16) {
        // LDS-transpose epilogue: coalesced u64 stores. Fences required: u16
        // writes then u64 reads of same LDS addrs (TBAA would allow reorder).
        __syncthreads();   // all waves done reading As/Bs
        u16* scr = ((wv < 2) ? As : Bs) + (wv & 1) * 2048;   // per-wave [16][68] u16
        u16* C = (u16*)Cv;
        #pragma unroll
        for (int mi = 0; mi < 4; ++mi) {
            #pragma unroll
            for (int ni = 0; ni < 4; ++ni) {
                const float bcol = bias[n0 + wc + ni * 16 + lr];
                #pragma unroll
                for (int r = 0; r < 4; ++r)
                    scr[(hi * 4 + r) * 68 + ni * 16 + lr] =
                        f32_to_bf16(acc[mi][ni][r] + bcol);
            }
            asm volatile("" ::: "memory");   // order: writes before reads
            #pragma unroll
            for (int i = 0; i < 4; ++i) {
                const int rl = i * 4 + hi;
                const u64 v = *(const u64*)(scr + rl * 68 + (lane & 15) * 4);
                *(u64*)(C + (size_t)(m0 + wr + mi * 16 + rl) * N
                          + n0 + wc + (lane & 15) * 4) = v;
            }
            asm volatile("" ::: "memory");   // order: reads before next overwrite
        }
    } else {
        const int col0 = n0 + wc + lr;
        #pragma unroll
        for (int ni = 0; ni < 4; ++ni) {
            const float bcol = bias[col0 + ni * 16];
            #pragma unroll
            for (int mi = 0; mi < 4; ++mi)
                #pragma unroll
                for (int r = 0; r < 4; ++r) {
                    const int row = m0 + wr + mi * 16 + hi * 4 + r;
                    ((float*)Cv)[(size_t)row * N + col0 + ni * 16] = acc[mi][ni][r] + bcol;
                }
        }
    }
}

// ---------------- rolled-neighbor offset table (np.nonzero order) ----------------
struct OffT { int dr[NROLL]; int dc[NROLL]; };
constexpr bool rvalid(int s, int r, int c) {
    return (s == 0) ? (r >= 4 || c >= 4) :
           (s == 1) ? (r >= 4 || c <= 2) :
           (s == 2) ? (r <= 2 || c >= 4) :
                      (r <= 2 || c <= 2);
}
constexpr OffT make_offt() {
    OffT t{};
    int p = 0;
    for (int s = 0; s < 4; ++s)
        for (int r = 0; r < 7; ++r)
            for (int c = 0; c < 7; ++c)
                if (rvalid(s, r, c)) {
                    const int sh = (s < 2) ? -3 : 3;
                    const int sw = (s & 1) ? 3 : -3;
                    t.dr[p] = r - sh;   // rolled[h] = orig[h - sh]
                    t.dc[p] = c - sw;
                    ++p;
                }
    return t;
}
__device__ constexpr OffT OFT = make_offt();

// ---------------- MFMA window attention, HEAD-PAIRED ----------------
// One block = (window, head-pair 2h/2h+1), heads processed sequentially reusing
// LDS. Heads (2h,2h+1) share 128B L1 lines (K at byte 1024+h*64 of the pixel
// row, pairs 128B-aligned) -> phase B's scattered gathers hit L1/L2 lines
// fetched by phase A. Per-phase body identical to r17/r18 (group-streamed,
// swapped QK^T, no-max softmax, deferred norm).
__global__ __launch_bounds__(256, 5) void attn_win(
    const u16* __restrict__ qkvb,    // (25088, 1536) bf16: q|k|v
    const float* __restrict__ bt,    // swapped-fragment bias table (x log2e)
    u16* __restrict__ aob)           // (25088, 512) bf16
{
    // Vt 12800 + Ps 8704 + pixt 724 = 22,228 B
    __shared__ __align__(16) u16 Vt[32 * VP];    // V transposed: [d][kv]
    __shared__ __align__(16) u16 Ps[64 * PSP];   // P bf16, unnormalized, 64-col window
    __shared__ int pixt[NKV];                    // head-INDEPENDENT pixel-row offsets

    const int tid  = threadIdx.x;
    const int lane = tid & 63, wv = tid >> 6;
    // XCD swizzle: 4096 blocks = 8 * 512
    const int bid  = blockIdx.x;
    const int nid  = (bid & 7) * (NWIN * 8 / 8) + (bid >> 3);
    const int w    = nid >> 3;
    const int hb   = (nid & 7) * 2;      // head pair base
    const int b    = w >> 6;
    const int h0   = ((w >> 3) & 7) * 7;
    const int w0c  = (w & 7) * 7;
    const int pixbase = b * 3136;

    // ---- pixel-row offset table (no head term) ----
    if (tid < NKV) {
        int h, wc;
        if (tid < WA) { h = h0 + tid / 7; wc = w0c + tid % 7; }
        else {
            const int i = tid - WA;
            h = h0 + OFT.dr[i];  h += (h < 0) ? 56 : 0;  h -= (h >= 56) ? 56 : 0;
            wc = w0c + OFT.dc[i]; wc += (wc < 0) ? 56 : 0; wc -= (wc >= 56) ? 56 : 0;
        }
        pixt[tid] = (pixbase + h * 56 + wc) * QKVLD;
    }
    __syncthreads();

    const int lr = lane & 15;
    const int hi = lane >> 4;
    const int lk = hi * 8;
    const int qrow0 = 16 * wv + hi * 4;   // + r (PV output rows)
    const float scale2 = 0.17677669529663687f * LOG2E;
    u16* const prow_ptr = Ps + (16 * wv + lr) * PSP;
    const u16* const parow = Ps + (16 * wv + lr) * PSP;

    #pragma unroll
    for (int hp = 0; hp < 2; ++hp) {
        const int head = hb + hp;
        const int hOff = head * HD;

        if (hp == 1) __syncthreads();   // phase A's PV reads of Vt complete

        // ---- V staging for this head: issue loads, then LDS writes ----
        u64 vdat[6];
        #pragma unroll
        for (int it = 0; it < 6; ++it) {
            const int idx = tid + it * 256;
            if (idx < NKV * 8)
                vdat[it] = *(const u64*)(qkvb + pixt[idx >> 3] + hOff + 2 * CDIM + (idx & 7) * 4);
        }
        #pragma unroll
        for (int it = 0; it < 6; ++it) {
            const int idx = tid + it * 256;
            if (idx < NKV * 8) {
                const int kv = idx >> 3, dq = idx & 7;         // d = dq*4 + j
                #pragma unroll
                for (int j = 0; j < 4; ++j)
                    Vt[(dq * 4 + j) * VP + kv] = (u16)(vdat[it] >> (16 * j));
            }
        }
        if (hp == 0)   // pad cols stay zero across phases
            for (int idx = tid; idx < 32 * (NKVT - NKV); idx += 256)
                Vt[(idx / (NKVT - NKV)) * VP + NKV + idx % (NKVT - NKV)] = 0;

        // ---- Q fragment + group-0 K prefetch ----
        const int qr = 16 * wv + lr;
        const short8 aq = *(const short8*)(qkvb + pixt[(qr < WA) ? qr : 0] + hOff + lk);
        short8 bk[2][4];
        #pragma unroll
        for (int j = 0; j < 4; ++j) {
            const int kvr = j * 16 + lr;
            bk[0][j] = *(const short8*)(qkvb + pixt[(kvr < NKV) ? kvr : 0] + hOff + CDIM + lk);
        }

        __syncthreads();   // Vt staging complete (before any PV read)

        const float* btb = bt + (((size_t)head * 4 + wv) * 12) * 256 + lane * 4;
        float t = 0.f;
        f32x4 o[2] = {{0.f, 0.f, 0.f, 0.f}, {0.f, 0.f, 0.f, 0.f}};

        #pragma unroll
        for (int g = 0; g < 3; ++g) {
            if (g < 2) {   // prefetch next group's K fragments (static buf index)
                #pragma unroll
                for (int j = 0; j < 4; ++j) {
                    const int kvr = (g + 1) * 64 + j * 16 + lr;
                    bk[(g + 1) & 1][j] =
                        *(const short8*)(qkvb + pixt[(kvr < NKV) ? kvr : 0] + hOff + CDIM + lk);
                }
            }
            f32x4 s4[4];
            __builtin_amdgcn_s_setprio(1);
            #pragma unroll
            for (int j = 0; j < 4; ++j)
                s4[j] = __builtin_amdgcn_mfma_f32_16x16x32_bf16(
                    bk[g & 1][j], aq, (f32x4){0.f, 0.f, 0.f, 0.f}, 0, 0, 0);
            __builtin_amdgcn_s_setprio(0);
            #pragma unroll
            for (int j = 0; j < 4; ++j) {
                const int n = g * 4 + j;
                const float4 b4 = *(const float4*)(btb + n * 256);
                const float e0 = exp2f(fmaf(s4[j][0], scale2, b4.x));
                const float e1 = exp2f(fmaf(s4[j][1], scale2, b4.y));
                const float e2 = exp2f(fmaf(s4[j][2], scale2, b4.z));
                const float e3 = exp2f(fmaf(s4[j][3], scale2, b4.w));
                t += (e0 + e1) + (e2 + e3);
                const u32 lo  = (u32)cvt_bf16_hw(e0) | ((u32)cvt_bf16_hw(e1) << 16);
                const u32 hi2 = (u32)cvt_bf16_hw(e2) | ((u32)cvt_bf16_hw(e3) << 16);
                *(u64*)(prow_ptr + j * 16 + hi * 4) = (u64)lo | ((u64)hi2 << 32);
            }
            asm volatile("" ::: "memory");   // Ps writes before pa reads (TBAA)
            __builtin_amdgcn_s_setprio(1);
            #pragma unroll
            for (int kkl = 0; kkl < 2; ++kkl) {
                const short8 pa = *(const short8*)(parow + kkl * 32 + lk);
                #pragma unroll
                for (int n0 = 0; n0 < 2; ++n0) {
                    const short8 vb = *(const short8*)(Vt + (n0 * 16 + lr) * VP + (g * 2 + kkl) * 32 + lk);
                    o[n0] = __builtin_amdgcn_mfma_f32_16x16x32_bf16(pa, vb, o[n0], 0, 0, 0);
                }
            }
            __builtin_amdgcn_s_setprio(0);
            asm volatile("" ::: "memory");   // pa reads before next group's overwrite
        }

        // ---- deferred normalization + store ----
        t += __shfl_xor(t, 16);
        t += __shfl_xor(t, 32);
        const float inv = 1.f / fmaxf(t, 1e-30f);
        float inv4[4];
        #pragma unroll
        for (int r = 0; r < 4; ++r)
            inv4[r] = __shfl(inv, (lane & 48) | (hi * 4 + r));

        #pragma unroll
        for (int n0 = 0; n0 < 2; ++n0)
            #pragma unroll
            for (int r = 0; r < 4; ++r) {
                const int qi = qrow0 + r;
                if (qi < WA)
                    aob[(size_t)(w * WA + qi) * CDIM + hOff + n0 * 16 + lr] =
                        cvt_bf16_hw(o[n0][r] * inv4[r]);
            }
    }
}

// ---------------- launch ----------------
extern "C" void kernel_launch(void* const* d_in, const int* in_sizes, int n_in,
                              void* d_out, int out_size, void* d_ws, size_t ws_size,
                              hipStream_t stream)
{
    const float* x      = (const float*)d_in[0];
    const float* qkv_w  = (const float*)d_in[1];
    const float* qkv_b  = (const float*)d_in[2];
    const float* proj_w = (const float*)d_in[3];
    const float* proj_b = (const float*)d_in[4];
    const float* rpbt   = (const float*)d_in[5];
    const float* rpbn   = (const float*)d_in[6];

    u16* xb   = (u16*)d_ws;                         // (25088, 512)
    u16* qkvb = xb + (size_t)NPIX * CDIM;           // (25088, 1536)
    u16* aob  = qkvb + (size_t)NPIX * QKVLD;        // (25088, 512)
    u16* qwb  = aob + (size_t)NPIX * CDIM;          // (1536, 512)
    u16* pwb  = qwb + (size_t)QKVLD * CDIM;         // (512, 512)
    float* bt = (float*)(pwb + (size_t)CDIM * CDIM);// 196608 floats
    const size_t need = ((size_t)NPIX * CDIM + (size_t)NPIX * QKVLD + (size_t)NPIX * CDIM
                         + (size_t)QKVLD * CDIM + (size_t)CDIM * CDIM) * sizeof(u16)
                        + (size_t)NHEADS * NKVT * 64 * sizeof(float);
    if (ws_size < need) return;

    {
        const int nx = NPIX * CDIM;           // 12,845,056
        const int nq = QKVLD * CDIM;          //    786,432
        const int np = CDIM * CDIM;           //    262,144
        const int tot4 = (nx + nq + np) / 4;
        cvt3_bf16<<<(tot4 + 255) / 256, 256, 0, stream>>>(
            x, xb, nx, qkv_w, qwb, nq, proj_w, pwb, np);
        build_bias<<<(NHEADS * NKVT * 64) / 256, 256, 0, stream>>>(rpbt, rpbn, bt);
    }

    // QKV projection (bf16 out), 1D grid 2352 = 8*294
    gemm_mfma<true><<<(NPIX / 128) * (QKVLD / 128), 256, 0, stream>>>(
        xb, qwb, qkv_b, qkvb, NPIX, QKVLD, CDIM);

    // windowed attention (bf16 out), head-paired: 4096 = 8*512 blocks
    attn_win<<<NWIN * 8, 256, 0, stream>>>(qkvb, bt, aob);

    // output projection (fp32 out), 1D grid 784 = 8*98
    gemm_mfma<false><<<(NPIX / 128) * (CDIM / 128), 256, 0, stream>>>(
        aob, pwb, proj_b, d_out, NPIX, CDIM, CDIM);
}

// Round 20
// 171.425 us; speedup vs baseline: 1.1095x; 1.1095x over previous
//
#include <hip/hip_runtime.h>
#include <hip/hip_bf16.h>
#include <math.h>

typedef unsigned short u16;
typedef unsigned int   u32;
typedef unsigned long long u64;
typedef __attribute__((ext_vector_type(8))) short short8;   // 8 bf16 (4 VGPR)
typedef __attribute__((ext_vector_type(4))) float f32x4;

// ---------------- problem constants ----------------
#define NHEADS 16
#define HD     32
#define WA     49
#define NROLL  132
#define NKV    181     // WA + NROLL
#define NKVT   192     // 12 tiles of 16
#define CDIM   512
#define QKVLD  1536
#define NPIX   25088   // 8*56*56
#define NWIN   512
// LDS pitches (bf16 elems)
#define VP  200       // Vt pitch
#define PSP 68        // Ps pitch (64 cols = one group + 4 pad)
#define LOG2E 1.4426950408889634f

__device__ __forceinline__ u16 f32_to_bf16(float f) {
    union { float f; u32 u; } x; x.f = f;
    u32 r = x.u + 0x7FFFu + ((x.u >> 16) & 1u);   // RNE
    return (u16)(r >> 16);
}
__device__ __forceinline__ u16 cvt_bf16_hw(float f) {
    __hip_bfloat16 h = __float2bfloat16(f);       // RNE
    return *reinterpret_cast<u16*>(&h);
}

// ---------------- fused fp32 -> bf16 conversion (3 buffers, 1 launch) ----------------
__global__ __launch_bounds__(256) void cvt3_bf16(
    const float* __restrict__ in0, u16* __restrict__ out0, int n0,
    const float* __restrict__ in1, u16* __restrict__ out1, int n1,
    const float* __restrict__ in2, u16* __restrict__ out2, int n2)
{
    int i = (blockIdx.x * 256 + threadIdx.x) * 4;
    const float* in; u16* out;
    if (i < n0)            { in = in0; out = out0; }
    else if (i < n0 + n1)  { in = in1; out = out1; i -= n0; }
    else if (i < n0 + n1 + n2) { in = in2; out = out2; i -= n0 + n1; }
    else return;
    float4 v = *(const float4*)(in + i);
    *(ushort4*)(out + i) = make_ushort4(f32_to_bf16(v.x), f32_to_bf16(v.y),
                                        f32_to_bf16(v.z), f32_to_bf16(v.w));
}

// ---------------- bias table, swapped-QK^T C-fragment order, pre-scaled by log2e ----------------
// bt[head][qt(4)][n(12)][lane(64)][r(4)]:
//   qi = qt*16 + (lane&15) ; kv = n*16 + (lane>>4)*4 + r.  Mask baked (-1e30*log2e).
__global__ __launch_bounds__(256) void build_bias(
    const float* __restrict__ rpbt,   // (169,16)
    const float* __restrict__ rpbn,   // (16,49,132)
    float* __restrict__ bt)
{
    const int idx  = blockIdx.x * 256 + threadIdx.x;
    const int h    = idx / 12288;            // 4*12*64*4
    const int rem  = idx % 12288;
    const int qt   = rem / 3072;             // 12*64*4
    const int rem2 = rem % 3072;
    const int n    = rem2 / 256;             // 64*4
    const int rem3 = rem2 % 256;
    const int lane = rem3 / 4;
    const int r    = rem3 % 4;
    const int qi = qt * 16 + (lane & 15);
    const int kv = n * 16 + (lane >> 4) * 4 + r;
    float v = -1e30f;
    if (qi < WA && kv < NKV) {
        if (kv < WA) {
            const int r1 = qi / 7, c1 = qi % 7, r2 = kv / 7, c2 = kv % 7;
            v = rpbt[((r1 - r2 + 6) * 13 + (c1 - c2 + 6)) * NHEADS + h];
        } else {
            v = rpbn[(h * WA + qi) * NROLL + (kv - WA)];
        }
    }
    bt[idx] = v * LOG2E;                     // fold log2e: attn uses exp2 directly
}

// ---------------- bf16 MFMA GEMM: C = A @ W^T + bias, BK=64 ----------------
// 1D grid with XCD-chunked swizzle (gridDim.x divisible by 8).
// __launch_bounds__(256,4): cap VGPR at 128 so 4 blocks/CU at 32KB LDS (r18: -21us).
template<bool STORE_BF16>
__global__ __launch_bounds__(256, 4) void gemm_mfma(
    const u16* __restrict__ A, const u16* __restrict__ W,
    const float* __restrict__ bias, void* __restrict__ Cv,
    int M, int N, int K)
{
    __shared__ __align__(16) u16 As[128 * 64];   // 16 KB
    __shared__ __align__(16) u16 Bs[128 * 64];   // 16 KB
    const int tid = threadIdx.x;
    const int lane = tid & 63, wv = tid >> 6;
    const int bid = blockIdx.x;
    const int nid = (bid & 7) * (gridDim.x >> 3) + (bid >> 3);
    const int nbx = N >> 7;
    const int m0 = (nid / nbx) * 128, n0 = (nid % nbx) * 128;
    const int wr = (wv >> 1) * 64, wc = (wv & 1) * 64;
    const int lr = lane & 15;
    const int lk = (lane >> 4) * 8;
    const int srow = lane >> 3;          // 0..7 within 8-row block
    const int scol = (lane & 7) * 8;     // 0..56 elems

    f32x4 acc[4][4] = {};

    for (int k0 = 0; k0 < K; k0 += 64) {
        __syncthreads();
        #pragma unroll
        for (int blk = 0; blk < 4; ++blk) {
            const int r = wv * 32 + blk * 8;     // 8 rows per instr (64 lanes x 16B = 1KB)
            __builtin_amdgcn_global_load_lds(
                (const __attribute__((address_space(1))) void*)
                    (A + (size_t)(m0 + r + srow) * K + k0 + scol),
                (__attribute__((address_space(3))) void*)(As + r * 64), 16, 0, 0);
            __builtin_amdgcn_global_load_lds(
                (const __attribute__((address_space(1))) void*)
                    (W + (size_t)(n0 + r + srow) * K + k0 + scol),
                (__attribute__((address_space(3))) void*)(Bs + r * 64), 16, 0, 0);
        }
        __syncthreads();
        #pragma unroll
        for (int kk = 0; kk < 2; ++kk) {
            short8 af[4], bf[4];
            #pragma unroll
            for (int mi = 0; mi < 4; ++mi)
                af[mi] = *(const short8*)(As + (wr + mi * 16 + lr) * 64 + kk * 32 + lk);
            #pragma unroll
            for (int ni = 0; ni < 4; ++ni)
                bf[ni] = *(const short8*)(Bs + (wc + ni * 16 + lr) * 64 + kk * 32 + lk);
            #pragma unroll
            for (int mi = 0; mi < 4; ++mi)
                #pragma unroll
                for (int ni = 0; ni < 4; ++ni)
                    acc[mi][ni] = __builtin_amdgcn_mfma_f32_16x16x32_bf16(af[mi], bf[ni], acc[mi][ni], 0, 0, 0);
        }
    }

    const int hi = lane >> 4;
    if (STORE_BF16) {
        // LDS-transpose epilogue: coalesced u64 stores. Fences required: u16
        // writes then u64 reads of same LDS addrs (TBAA would allow reorder).
        __syncthreads();   // all waves done reading As/Bs
        u16* scr = ((wv < 2) ? As : Bs) + (wv & 1) * 2048;   // per-wave [16][68] u16
        u16* C = (u16*)Cv;
        #pragma unroll
        for (int mi = 0; mi < 4; ++mi) {
            #pragma unroll
            for (int ni = 0; ni < 4; ++ni) {
                const float bcol = bias[n0 + wc + ni * 16 + lr];
                #pragma unroll
                for (int r = 0; r < 4; ++r)
                    scr[(hi * 4 + r) * 68 + ni * 16 + lr] =
                        f32_to_bf16(acc[mi][ni][r] + bcol);
            }
            asm volatile("" ::: "memory");   // order: writes before reads
            #pragma unroll
            for (int i = 0; i < 4; ++i) {
                const int rl = i * 4 + hi;
                const u64 v = *(const u64*)(scr + rl * 68 + (lane & 15) * 4);
                *(u64*)(C + (size_t)(m0 + wr + mi * 16 + rl) * N
                          + n0 + wc + (lane & 15) * 4) = v;
            }
            asm volatile("" ::: "memory");   // order: reads before next overwrite
        }
    } else {
        const int col0 = n0 + wc + lr;
        #pragma unroll
        for (int ni = 0; ni < 4; ++ni) {
            const float bcol = bias[col0 + ni * 16];
            #pragma unroll
            for (int mi = 0; mi < 4; ++mi)
                #pragma unroll
                for (int r = 0; r < 4; ++r) {
                    const int row = m0 + wr + mi * 16 + hi * 4 + r;
                    ((float*)Cv)[(size_t)row * N + col0 + ni * 16] = acc[mi][ni][r] + bcol;
                }
        }
    }
}

// ---------------- rolled-neighbor offset table (np.nonzero order) ----------------
struct OffT { int dr[NROLL]; int dc[NROLL]; };
constexpr bool rvalid(int s, int r, int c) {
    return (s == 0) ? (r >= 4 || c >= 4) :
           (s == 1) ? (r >= 4 || c <= 2) :
           (s == 2) ? (r <= 2 || c >= 4) :
                      (r <= 2 || c <= 2);
}
constexpr OffT make_offt() {
    OffT t{};
    int p = 0;
    for (int s = 0; s < 4; ++s)
        for (int r = 0; r < 7; ++r)
            for (int c = 0; c < 7; ++c)
                if (rvalid(s, r, c)) {
                    const int sh = (s < 2) ? -3 : 3;
                    const int sw = (s & 1) ? 3 : -3;
                    t.dr[p] = r - sh;   // rolled[h] = orig[h - sh]
                    t.dc[p] = c - sw;
                    ++p;
                }
    return t;
}
__device__ constexpr OffT OFT = make_offt();

// ---------------- MFMA window attention (floor: 83us across 5 variants) ----------------
// Swapped QK^T, no-max softmax, group-streamed (3x4 K-tiles), deferred norm.
__global__ __launch_bounds__(256, 5) void attn_win(
    const u16* __restrict__ qkvb,    // (25088, 1536) bf16: q|k|v
    const float* __restrict__ bt,    // swapped-fragment bias table (x log2e)
    u16* __restrict__ aob)           // (25088, 512) bf16
{
    // Vt 12800 + Ps 8704 + pixt 724 = 22,228 B
    __shared__ __align__(16) u16 Vt[32 * VP];    // V transposed: [d][kv]
    __shared__ __align__(16) u16 Ps[64 * PSP];   // P bf16, unnormalized, 64-col window
    __shared__ int pixt[NKV];

    const int tid  = threadIdx.x;
    const int lane = tid & 63, wv = tid >> 6;
    // XCD swizzle: contiguous (window, head) chunk per XCD -> K/V L2 reuse
    const int bid  = blockIdx.x;
    const int nid  = (bid & 7) * (NWIN * NHEADS / 8) + (bid >> 3);
    const int w    = nid >> 4;
    const int head = nid & 15;
    const int b    = w >> 6;
    const int h0   = ((w >> 3) & 7) * 7;
    const int w0c  = (w & 7) * 7;
    const int pixbase = b * 3136;

    // ---- pixel-row offset table ----
    if (tid < NKV) {
        int h, wc;
        if (tid < WA) { h = h0 + tid / 7; wc = w0c + tid % 7; }
        else {
            const int i = tid - WA;
            h = h0 + OFT.dr[i];  h += (h < 0) ? 56 : 0;  h -= (h >= 56) ? 56 : 0;
            wc = w0c + OFT.dc[i]; wc += (wc < 0) ? 56 : 0; wc -= (wc >= 56) ? 56 : 0;
        }
        pixt[tid] = (pixbase + h * 56 + wc) * QKVLD + head * HD;
    }
    __syncthreads();

    const int lr = lane & 15;
    const int hi = lane >> 4;
    const int lk = hi * 8;
    const int qrow0 = 16 * wv + hi * 4;   // + r (PV output rows)

    // ---- Q fragment direct from global ----
    const int qr = 16 * wv + lr;
    const short8 aq = *(const short8*)(qkvb + pixt[(qr < WA) ? qr : 0] + lk);

    // ---- V staging: issue all global loads first, then LDS writes ----
    u64 vdat[6];
    #pragma unroll
    for (int it = 0; it < 6; ++it) {
        const int idx = tid + it * 256;
        if (idx < NKV * 8)
            vdat[it] = *(const u64*)(qkvb + pixt[idx >> 3] + 2 * CDIM + (idx & 7) * 4);
    }
    #pragma unroll
    for (int it = 0; it < 6; ++it) {
        const int idx = tid + it * 256;
        if (idx < NKV * 8) {
            const int kv = idx >> 3, dq = idx & 7;             // d = dq*4 + j
            #pragma unroll
            for (int j = 0; j < 4; ++j)
                Vt[(dq * 4 + j) * VP + kv] = (u16)(vdat[it] >> (16 * j));
        }
    }
    for (int idx = tid; idx < 32 * (NKVT - NKV); idx += 256)
        Vt[(idx / (NKVT - NKV)) * VP + NKV + idx % (NKVT - NKV)] = 0;

    // ---- prefetch group 0's K fragments (pad cols read row 0; bias masks them) ----
    short8 bk[2][4];
    #pragma unroll
    for (int j = 0; j < 4; ++j) {
        const int kvr = j * 16 + lr;
        bk[0][j] = *(const short8*)(qkvb + pixt[(kvr < NKV) ? kvr : 0] + CDIM + lk);
    }

    __syncthreads();   // Vt staging complete (before any PV read)

    const float scale2 = 0.17677669529663687f * LOG2E;
    const float* btb = bt + (((size_t)head * 4 + wv) * 12) * 256 + lane * 4;
    u16* const prow_ptr = Ps + (16 * wv + lr) * PSP;   // write base (col += j*16 + hi*4)
    const u16* const parow = Ps + (16 * wv + lr) * PSP;
    float t = 0.f;
    f32x4 o[2] = {{0.f, 0.f, 0.f, 0.f}, {0.f, 0.f, 0.f, 0.f}};

    #pragma unroll
    for (int g = 0; g < 3; ++g) {
        // prefetch next group's K fragments (g is compile-time: static buffer index)
        if (g < 2) {
            #pragma unroll
            for (int j = 0; j < 4; ++j) {
                const int kvr = (g + 1) * 64 + j * 16 + lr;
                bk[(g + 1) & 1][j] =
                    *(const short8*)(qkvb + pixt[(kvr < NKV) ? kvr : 0] + CDIM + lk);
            }
        }
        // 4 QK^T MFMAs for this group
        f32x4 s4[4];
        __builtin_amdgcn_s_setprio(1);
        #pragma unroll
        for (int j = 0; j < 4; ++j)
            s4[j] = __builtin_amdgcn_mfma_f32_16x16x32_bf16(
                bk[g & 1][j], aq, (f32x4){0.f, 0.f, 0.f, 0.f}, 0, 0, 0);
        __builtin_amdgcn_s_setprio(0);
        // bias -> exp2 -> t -> pack -> Ps (unnormalized), cols j*16+hi*4
        #pragma unroll
        for (int j = 0; j < 4; ++j) {
            const int n = g * 4 + j;
            const float4 b4 = *(const float4*)(btb + n * 256);
            const float e0 = exp2f(fmaf(s4[j][0], scale2, b4.x));
            const float e1 = exp2f(fmaf(s4[j][1], scale2, b4.y));
            const float e2 = exp2f(fmaf(s4[j][2], scale2, b4.z));
            const float e3 = exp2f(fmaf(s4[j][3], scale2, b4.w));
            t += (e0 + e1) + (e2 + e3);
            const u32 lo  = (u32)cvt_bf16_hw(e0) | ((u32)cvt_bf16_hw(e1) << 16);
            const u32 hi2 = (u32)cvt_bf16_hw(e2) | ((u32)cvt_bf16_hw(e3) << 16);
            *(u64*)(prow_ptr + j * 16 + hi * 4) = (u64)lo | ((u64)hi2 << 32);
        }
        asm volatile("" ::: "memory");   // Ps writes before pa reads (TBAA)
        // 2 PV chunks for this group (kv = g*64 + kkl*32 ..)
        __builtin_amdgcn_s_setprio(1);
        #pragma unroll
        for (int kkl = 0; kkl < 2; ++kkl) {
            const short8 pa = *(const short8*)(parow + kkl * 32 + lk);
            #pragma unroll
            for (int n0 = 0; n0 < 2; ++n0) {
                const short8 vb = *(const short8*)(Vt + (n0 * 16 + lr) * VP + (g * 2 + kkl) * 32 + lk);
                o[n0] = __builtin_amdgcn_mfma_f32_16x16x32_bf16(pa, vb, o[n0], 0, 0, 0);
            }
        }
        __builtin_amdgcn_s_setprio(0);
        asm volatile("" ::: "memory");   // pa reads before next group's overwrite
    }

    // ---- deferred normalization ----
    t += __shfl_xor(t, 16);
    t += __shfl_xor(t, 32);
    const float inv = 1.f / fmaxf(t, 1e-30f);   // fn of lr only (uniform in hi)
    float inv4[4];
    #pragma unroll
    for (int r = 0; r < 4; ++r)
        inv4[r] = __shfl(inv, (lane & 48) | (hi * 4 + r));

    #pragma unroll
    for (int n0 = 0; n0 < 2; ++n0)
        #pragma unroll
        for (int r = 0; r < 4; ++r) {
            const int qi = qrow0 + r;
            if (qi < WA)
                aob[(size_t)(w * WA + qi) * CDIM + head * HD + n0 * 16 + lr] =
                    cvt_bf16_hw(o[n0][r] * inv4[r]);
        }
}

// ---------------- launch ----------------
extern "C" void kernel_launch(void* const* d_in, const int* in_sizes, int n_in,
                              void* d_out, int out_size, void* d_ws, size_t ws_size,
                              hipStream_t stream)
{
    const float* x      = (const float*)d_in[0];
    const float* qkv_w  = (const float*)d_in[1];
    const float* qkv_b  = (const float*)d_in[2];
    const float* proj_w = (const float*)d_in[3];
    const float* proj_b = (const float*)d_in[4];
    const float* rpbt   = (const float*)d_in[5];
    const float* rpbn   = (const float*)d_in[6];

    u16* xb   = (u16*)d_ws;                         // (25088, 512)
    u16* qkvb = xb + (size_t)NPIX * CDIM;           // (25088, 1536)
    u16* aob  = qkvb + (size_t)NPIX * QKVLD;        // (25088, 512)
    u16* qwb  = aob + (size_t)NPIX * CDIM;          // (1536, 512)
    u16* pwb  = qwb + (size_t)QKVLD * CDIM;         // (512, 512)
    float* bt = (float*)(pwb + (size_t)CDIM * CDIM);// 196608 floats
    const size_t need = ((size_t)NPIX * CDIM + (size_t)NPIX * QKVLD + (size_t)NPIX * CDIM
                         + (size_t)QKVLD * CDIM + (size_t)CDIM * CDIM) * sizeof(u16)
                        + (size_t)NHEADS * NKVT * 64 * sizeof(float);
    if (ws_size < need) return;

    {
        const int nx = NPIX * CDIM;           // 12,845,056
        const int nq = QKVLD * CDIM;          //    786,432
        const int np = CDIM * CDIM;           //    262,144
        const int tot4 = (nx + nq + np) / 4;
        cvt3_bf16<<<(tot4 + 255) / 256, 256, 0, stream>>>(
            x, xb, nx, qkv_w, qwb, nq, proj_w, pwb, np);
        build_bias<<<(NHEADS * NKVT * 64) / 256, 256, 0, stream>>>(rpbt, rpbn, bt);
    }

    // QKV projection (bf16 out), 1D grid 2352 = 8*294
    gemm_mfma<true><<<(NPIX / 128) * (QKVLD / 128), 256, 0, stream>>>(
        xb, qwb, qkv_b, qkvb, NPIX, QKVLD, CDIM);

    // windowed attention (bf16 out)
    attn_win<<<NWIN * NHEADS, 256, 0, stream>>>(qkvb, bt, aob);

    // output projection (fp32 out), 1D grid 784 = 8*98
    gemm_mfma<false><<<(NPIX / 128) * (CDIM / 128), 256, 0, stream>>>(
        aob, pwb, proj_b, d_out, NPIX, CDIM, CDIM);
}